// Round 1
// baseline (795.268 us; speedup 1.0000x reference)
//
#include <hip/hip_runtime.h>

#define NBATCH 4
#define CIN 256
#define CATT 32
#define NPIX 4096

static constexpr float LOG2E_F = 1.4426950408889634f;

// ---------------------------------------------------------------------------
// K1: projection  out[b][o][n] = scale * (sum_c W[o][c] x[b][c][n] + bias[o])
// grid (NPIX/128, OC/32, NBATCH), block 256
// scale = cscale * (*pscale if pscale) ; q gets LOG2E folded in, v gets gamma.
// ---------------------------------------------------------------------------
__global__ __launch_bounds__(256, 2)
void proj_kernel(const float* __restrict__ W, const float* __restrict__ bias,
                 const float* __restrict__ x, float* __restrict__ out,
                 int OC, float cscale, const float* __restrict__ pscale)
{
    __shared__ float sW[32][33];
    __shared__ float sX[32][128];
    const int t = threadIdx.x;
    const int nblk = blockIdx.x * 128;
    const int oblk = blockIdx.y * 32;
    const int b = blockIdx.z;
    const float* xb = x + (size_t)b * CIN * NPIX;

    const int tx = t & 31;        // n-group: n0 = 4*tx
    const int ty = t >> 5;        // o-group: o0 = 4*ty
    float acc[4][4] = {};

    for (int c0 = 0; c0 < CIN; c0 += 32) {
        __syncthreads();
        { // W tile 32x32
            const int r = t >> 3, c4 = (t & 7) << 2;
            const float4 w4 = *reinterpret_cast<const float4*>(&W[(size_t)(oblk + r) * CIN + c0 + c4]);
            sW[r][c4]   = w4.x; sW[r][c4+1] = w4.y; sW[r][c4+2] = w4.z; sW[r][c4+3] = w4.w;
        }
        #pragma unroll
        for (int rr = 0; rr < 4; ++rr) { // X tile 32x128
            const int r = (t >> 5) + (rr << 3);
            const int c4 = (t & 31) << 2;
            *reinterpret_cast<float4*>(&sX[r][c4]) =
                *reinterpret_cast<const float4*>(&xb[(size_t)(c0 + r) * NPIX + nblk + c4]);
        }
        __syncthreads();
        #pragma unroll
        for (int kk = 0; kk < 32; ++kk) {
            float wv[4];
            #pragma unroll
            for (int oo = 0; oo < 4; ++oo) wv[oo] = sW[(ty << 2) + oo][kk];
            const float4 xx = *reinterpret_cast<const float4*>(&sX[kk][tx << 2]);
            const float xv[4] = {xx.x, xx.y, xx.z, xx.w};
            #pragma unroll
            for (int oo = 0; oo < 4; ++oo)
                #pragma unroll
                for (int nn = 0; nn < 4; ++nn)
                    acc[oo][nn] = fmaf(wv[oo], xv[nn], acc[oo][nn]);
        }
    }
    const float scale = cscale * (pscale ? pscale[0] : 1.0f);
    #pragma unroll
    for (int oo = 0; oo < 4; ++oo) {
        const int o = oblk + (ty << 2) + oo;
        const float bb = bias[o];
        float4 r4;
        r4.x = scale * (acc[oo][0] + bb);
        r4.y = scale * (acc[oo][1] + bb);
        r4.z = scale * (acc[oo][2] + bb);
        r4.w = scale * (acc[oo][3] + bb);
        *reinterpret_cast<float4*>(&out[((size_t)b * OC + o) * NPIX + nblk + (tx << 2)]) = r4;
    }
}

// ---------------------------------------------------------------------------
// K2: rs[b][j] = 1 / sum_i exp2( sum_a q[b][a][i] * k[b][a][j] )
// (q pre-scaled by log2(e), so exp2 == softmax's exp; max-subtraction skipped:
//  |logits| <= ~60 -> exp2 fits fp32 easily, sum > 0 always)
// grid (NPIX/32, NBATCH), block 256
// ---------------------------------------------------------------------------
__global__ __launch_bounds__(256, 2)
void stats_kernel(const float* __restrict__ q, const float* __restrict__ k,
                  float* __restrict__ rs)
{
    __shared__ float sK[32][36];   // [a][j], pad keeps float4 alignment, bank shift 4
    __shared__ float sQ[32][68];   // [a][i], pad mult-of-4
    __shared__ float red[32][33];
    const int t = threadIdx.x;
    const int jblk = blockIdx.x * 32;
    const int b = blockIdx.y;
    const float* qb = q + (size_t)b * CATT * NPIX;
    const float* kb = k + (size_t)b * CATT * NPIX;

    { // K tile 32a x 32j, staged once
        const int r = t >> 3, c4 = (t & 7) << 2;
        *reinterpret_cast<float4*>(&sK[r][c4]) =
            *reinterpret_cast<const float4*>(&kb[(size_t)r * NPIX + jblk + c4]);
    }
    const int tx = t & 7;    // j group: j0 = 4*tx
    const int ty = t >> 3;   // i pair:  i0 = 2*ty
    float s_loc[4] = {0.f, 0.f, 0.f, 0.f};

    for (int iblk = 0; iblk < NPIX; iblk += 64) {
        __syncthreads();
        #pragma unroll
        for (int rr = 0; rr < 2; ++rr) {  // Q tile 32a x 64i
            const int r = (t >> 4) + (rr << 4);
            const int c4 = (t & 15) << 2;
            *reinterpret_cast<float4*>(&sQ[r][c4]) =
                *reinterpret_cast<const float4*>(&qb[(size_t)r * NPIX + iblk + c4]);
        }
        __syncthreads();
        float e[2][4] = {};
        #pragma unroll 8
        for (int a = 0; a < 32; ++a) {
            const float2 qq = *reinterpret_cast<const float2*>(&sQ[a][ty << 1]);
            const float4 k4 = *reinterpret_cast<const float4*>(&sK[a][tx << 2]);
            e[0][0] = fmaf(qq.x, k4.x, e[0][0]); e[0][1] = fmaf(qq.x, k4.y, e[0][1]);
            e[0][2] = fmaf(qq.x, k4.z, e[0][2]); e[0][3] = fmaf(qq.x, k4.w, e[0][3]);
            e[1][0] = fmaf(qq.y, k4.x, e[1][0]); e[1][1] = fmaf(qq.y, k4.y, e[1][1]);
            e[1][2] = fmaf(qq.y, k4.z, e[1][2]); e[1][3] = fmaf(qq.y, k4.w, e[1][3]);
        }
        #pragma unroll
        for (int ii = 0; ii < 2; ++ii)
            #pragma unroll
            for (int jj = 0; jj < 4; ++jj)
                s_loc[jj] += __builtin_amdgcn_exp2f(e[ii][jj]);
    }
    __syncthreads();
    #pragma unroll
    for (int jj = 0; jj < 4; ++jj) red[ty][(tx << 2) + jj] = s_loc[jj];
    __syncthreads();
    if (t < 32) {
        float s = 0.f;
        #pragma unroll
        for (int r = 0; r < 32; ++r) s += red[r][t];
        rs[(size_t)b * NPIX + jblk + t] = 1.0f / s;
    }
}

// ---------------------------------------------------------------------------
// K3: out[b][c][i] = x[b][c][i] + sum_j exp2(e[i][j]) * (v[c][j]*rs[j])
// block: 64 i x 128 c, loops j in steps of 32.  grid (NPIX/64, 2, NBATCH)
// ---------------------------------------------------------------------------
__global__ __launch_bounds__(256, 2)
void out_kernel(const float* __restrict__ q, const float* __restrict__ k,
                const float* __restrict__ v, const float* __restrict__ rs,
                const float* __restrict__ x, float* __restrict__ out)
{
    __shared__ float sQ[32][68];    // [a][i] 64i
    __shared__ float sK[32][36];    // [a][j] 32j
    __shared__ float sVT[32][132];  // [j][c] 128c
    __shared__ float sP[32][68];    // [j][i] 64i
    const int t = threadIdx.x;
    const int iblk = blockIdx.x * 64;
    const int cbase = blockIdx.y * 128;
    const int b = blockIdx.z;
    const float* qb = q + (size_t)b * CATT * NPIX;
    const float* kb = k + (size_t)b * CATT * NPIX;
    const float* vb = v + (size_t)b * CIN * NPIX;
    const float* rsb = rs + (size_t)b * NPIX;

    #pragma unroll
    for (int rr = 0; rr < 2; ++rr) { // Q tile staged once: 32a x 64i
        const int r = (t >> 4) + (rr << 4);
        const int c4 = (t & 15) << 2;
        *reinterpret_cast<float4*>(&sQ[r][c4]) =
            *reinterpret_cast<const float4*>(&qb[(size_t)r * NPIX + iblk + c4]);
    }
    const int ex = t & 7;     // E map: j0 = 4*ex
    const int ey = t >> 3;    //        i0 = 2*ey
    const int tx = t & 15;    // PV map: c = 4*tx + 64*u2 + uu
    const int ty = t >> 4;    //         i = 4*ty + ii
    float acc[2][4][4] = {};  // [u2][uu][ii]

    for (int jblk = 0; jblk < NPIX; jblk += 32) {
        __syncthreads();
        { // K tile 32a x 32j
            const int r = t >> 3, c4 = (t & 7) << 2;
            *reinterpret_cast<float4*>(&sK[r][c4]) =
                *reinterpret_cast<const float4*>(&kb[(size_t)r * NPIX + jblk + c4]);
        }
        { // VT tile: transpose 128c x 32j -> sVT[j][c], fused * rs[j]
            const int j4 = (t & 7) << 2;
            float rs4[4];
            #pragma unroll
            for (int jj = 0; jj < 4; ++jj) rs4[jj] = rsb[jblk + j4 + jj];
            #pragma unroll
            for (int rr = 0; rr < 4; ++rr) {
                const int cr = (t >> 3) + (rr << 5);   // 0..127
                const float4 v4 = *reinterpret_cast<const float4*>(&vb[(size_t)(cbase + cr) * NPIX + jblk + j4]);
                sVT[j4 + 0][cr] = v4.x * rs4[0];
                sVT[j4 + 1][cr] = v4.y * rs4[1];
                sVT[j4 + 2][cr] = v4.z * rs4[2];
                sVT[j4 + 3][cr] = v4.w * rs4[3];
            }
        }
        __syncthreads();
        { // E: 64i x 32j, per thread 2i x 4j -> P = exp2(E) into sP[j][i]
            float e[2][4] = {};
            #pragma unroll 8
            for (int a = 0; a < 32; ++a) {
                const float2 qq = *reinterpret_cast<const float2*>(&sQ[a][ey << 1]);
                const float4 k4 = *reinterpret_cast<const float4*>(&sK[a][ex << 2]);
                e[0][0] = fmaf(qq.x, k4.x, e[0][0]); e[0][1] = fmaf(qq.x, k4.y, e[0][1]);
                e[0][2] = fmaf(qq.x, k4.z, e[0][2]); e[0][3] = fmaf(qq.x, k4.w, e[0][3]);
                e[1][0] = fmaf(qq.y, k4.x, e[1][0]); e[1][1] = fmaf(qq.y, k4.y, e[1][1]);
                e[1][2] = fmaf(qq.y, k4.z, e[1][2]); e[1][3] = fmaf(qq.y, k4.w, e[1][3]);
            }
            #pragma unroll
            for (int jj = 0; jj < 4; ++jj) {
                float2 p2;
                p2.x = __builtin_amdgcn_exp2f(e[0][jj]);
                p2.y = __builtin_amdgcn_exp2f(e[1][jj]);
                *reinterpret_cast<float2*>(&sP[(ex << 2) + jj][ey << 1]) = p2;
            }
        }
        __syncthreads();
        { // PV: acc += P[j][i] * vt[j][c]
            #pragma unroll 4
            for (int j = 0; j < 32; ++j) {
                const float4 p4 = *reinterpret_cast<const float4*>(&sP[j][ty << 2]);
                const float pv[4] = {p4.x, p4.y, p4.z, p4.w};
                #pragma unroll
                for (int u2 = 0; u2 < 2; ++u2) {
                    const float4 vv = *reinterpret_cast<const float4*>(&sVT[j][(tx << 2) + (u2 << 6)]);
                    const float vvv[4] = {vv.x, vv.y, vv.z, vv.w};
                    #pragma unroll
                    for (int uu = 0; uu < 4; ++uu)
                        #pragma unroll
                        for (int ii = 0; ii < 4; ++ii)
                            acc[u2][uu][ii] = fmaf(vvv[uu], pv[ii], acc[u2][uu][ii]);
                }
            }
        }
    }
    // epilogue: out = acc + x   (gamma already folded into v)
    #pragma unroll
    for (int u2 = 0; u2 < 2; ++u2)
        #pragma unroll
        for (int uu = 0; uu < 4; ++uu) {
            const int c = cbase + (tx << 2) + (u2 << 6) + uu;
            const size_t base = ((size_t)b * CIN + c) * NPIX + iblk + (ty << 2);
            const float4 xx = *reinterpret_cast<const float4*>(&x[base]);
            float4 r4;
            r4.x = acc[u2][uu][0] + xx.x;
            r4.y = acc[u2][uu][1] + xx.y;
            r4.z = acc[u2][uu][2] + xx.z;
            r4.w = acc[u2][uu][3] + xx.w;
            *reinterpret_cast<float4*>(&out[base]) = r4;
        }
}

// ---------------------------------------------------------------------------
extern "C" void kernel_launch(void* const* d_in, const int* in_sizes, int n_in,
                              void* d_out, int out_size, void* d_ws, size_t ws_size,
                              hipStream_t stream)
{
    const float* x     = (const float*)d_in[0];
    const float* Wq    = (const float*)d_in[1];
    const float* bq    = (const float*)d_in[2];
    const float* Wk    = (const float*)d_in[3];
    const float* bk    = (const float*)d_in[4];
    const float* Wv    = (const float*)d_in[5];
    const float* bv    = (const float*)d_in[6];
    const float* gamma = (const float*)d_in[7];
    float* out = (float*)d_out;

    // workspace layout (floats): q | k | v' (=gamma*v) | rs  ~= 21 MB
    float* ws  = (float*)d_ws;
    float* qw  = ws;
    float* kw  = qw + (size_t)NBATCH * CATT * NPIX;
    float* vw  = kw + (size_t)NBATCH * CATT * NPIX;
    float* rsw = vw + (size_t)NBATCH * CIN * NPIX;

    dim3 blk(256);
    proj_kernel<<<dim3(NPIX / 128, CATT / 32, NBATCH), blk, 0, stream>>>(Wq, bq, x, qw, CATT, LOG2E_F, nullptr);
    proj_kernel<<<dim3(NPIX / 128, CATT / 32, NBATCH), blk, 0, stream>>>(Wk, bk, x, kw, CATT, 1.0f, nullptr);
    proj_kernel<<<dim3(NPIX / 128, CIN / 32,  NBATCH), blk, 0, stream>>>(Wv, bv, x, vw, CIN, 1.0f, gamma);
    stats_kernel<<<dim3(NPIX / 32, NBATCH), blk, 0, stream>>>(qw, kw, rsw);
    out_kernel<<<dim3(NPIX / 64, 2, NBATCH), blk, 0, stream>>>(qw, kw, vw, rsw, x, out);
}

// Round 2
// 200.562 us; speedup vs baseline: 3.9652x; 3.9652x over previous
//
#include <hip/hip_runtime.h>

#define NBATCH 4
#define CIN 256
#define CATT 32
#define NPIX 4096

static constexpr float LOG2E_F = 1.4426950408889634f;

typedef __attribute__((ext_vector_type(8))) short bf16x8;
typedef __attribute__((ext_vector_type(4))) float f32x4;

__device__ __forceinline__ unsigned short f2bf_rne(float f) {
    unsigned u = __builtin_bit_cast(unsigned, f);
    return (unsigned short)((u + 0x7fffu + ((u >> 16) & 1u)) >> 16);
}

// ---------------------------------------------------------------------------
// K1: fused q/k projection -> transposed bf16 outputs qt[b][n][32], kt[b][n][32]
// q gets LOG2E folded.  grid (NPIX/128, NBATCH), block 256.
// ---------------------------------------------------------------------------
__global__ __launch_bounds__(256, 2)
void proj_qk_kernel(const float* __restrict__ Wq, const float* __restrict__ bq,
                    const float* __restrict__ Wk, const float* __restrict__ bk,
                    const float* __restrict__ x,
                    unsigned short* __restrict__ qt, unsigned short* __restrict__ kt)
{
    __shared__ float sWq[32][33];
    __shared__ float sWk[32][33];
    __shared__ float sX[32][128];
    const int t = threadIdx.x;
    const int nblk = blockIdx.x * 128;
    const int b = blockIdx.y;
    const float* xb = x + (size_t)b * CIN * NPIX;
    const int tx = t & 31, ty = t >> 5;
    float aq[4][4] = {}, ak[4][4] = {};

    for (int c0 = 0; c0 < CIN; c0 += 32) {
        __syncthreads();
        {
            const int r = t >> 3, c4 = (t & 7) << 2;
            float4 w4 = *reinterpret_cast<const float4*>(&Wq[(size_t)r * CIN + c0 + c4]);
            sWq[r][c4] = w4.x; sWq[r][c4+1] = w4.y; sWq[r][c4+2] = w4.z; sWq[r][c4+3] = w4.w;
            w4 = *reinterpret_cast<const float4*>(&Wk[(size_t)r * CIN + c0 + c4]);
            sWk[r][c4] = w4.x; sWk[r][c4+1] = w4.y; sWk[r][c4+2] = w4.z; sWk[r][c4+3] = w4.w;
        }
        #pragma unroll
        for (int rr = 0; rr < 4; ++rr) {
            const int r = (t >> 5) + (rr << 3);
            const int c4 = (t & 31) << 2;
            *reinterpret_cast<float4*>(&sX[r][c4]) =
                *reinterpret_cast<const float4*>(&xb[(size_t)(c0 + r) * NPIX + nblk + c4]);
        }
        __syncthreads();
        #pragma unroll
        for (int kk = 0; kk < 32; ++kk) {
            float wq[4], wk[4];
            #pragma unroll
            for (int oo = 0; oo < 4; ++oo) { wq[oo] = sWq[(ty << 2) + oo][kk]; wk[oo] = sWk[(ty << 2) + oo][kk]; }
            const float4 xx = *reinterpret_cast<const float4*>(&sX[kk][tx << 2]);
            const float xv[4] = {xx.x, xx.y, xx.z, xx.w};
            #pragma unroll
            for (int oo = 0; oo < 4; ++oo)
                #pragma unroll
                for (int nn = 0; nn < 4; ++nn) {
                    aq[oo][nn] = fmaf(wq[oo], xv[nn], aq[oo][nn]);
                    ak[oo][nn] = fmaf(wk[oo], xv[nn], ak[oo][nn]);
                }
        }
    }
    float bqv[4], bkv[4];
    #pragma unroll
    for (int oo = 0; oo < 4; ++oo) { bqv[oo] = bq[(ty << 2) + oo]; bkv[oo] = bk[(ty << 2) + oo]; }
    #pragma unroll
    for (int nn = 0; nn < 4; ++nn) {
        const int n = nblk + (tx << 2) + nn;
        ushort4 uq, uk;
        uq.x = f2bf_rne(LOG2E_F * (aq[0][nn] + bqv[0]));
        uq.y = f2bf_rne(LOG2E_F * (aq[1][nn] + bqv[1]));
        uq.z = f2bf_rne(LOG2E_F * (aq[2][nn] + bqv[2]));
        uq.w = f2bf_rne(LOG2E_F * (aq[3][nn] + bqv[3]));
        uk.x = f2bf_rne(ak[0][nn] + bkv[0]);
        uk.y = f2bf_rne(ak[1][nn] + bkv[1]);
        uk.z = f2bf_rne(ak[2][nn] + bkv[2]);
        uk.w = f2bf_rne(ak[3][nn] + bkv[3]);
        const size_t base = ((size_t)b * NPIX + n) * CATT + (ty << 2);
        *reinterpret_cast<ushort4*>(&qt[base]) = uq;
        *reinterpret_cast<ushort4*>(&kt[base]) = uk;
    }
}

// ---------------------------------------------------------------------------
// K2: stats via MFMA.  rs[b][j] = 1 / sum_i exp2(E^T[j,i]).
// E^T tile: A = k^T (m=j), B = q^T (n=i), K = a = 32 (one MFMA).
// grid 256 (XCD-swizzled), block 256 (4 waves, wave w owns 16 j).
// ---------------------------------------------------------------------------
__global__ __launch_bounds__(256, 2)
void stats_kernel(const unsigned short* __restrict__ qt,
                  const unsigned short* __restrict__ kt, float* __restrict__ rs)
{
    const int n = blockIdx.x;
    const int b = (n & 7) >> 1;
    const int jt = ((n >> 3) << 1) + (n & 1);
    const int jblk = jt * 64;
    const int t = threadIdx.x, w = t >> 6, l = t & 63, lr = l & 15, lg = l >> 4;
    const unsigned short* qb = qt + (size_t)b * NPIX * CATT;
    const unsigned short* kb = kt + (size_t)b * NPIX * CATT;

    const bf16x8 kfrag = *reinterpret_cast<const bf16x8*>(
        &kb[(size_t)(jblk + 16 * w + lr) * CATT + lg * 8]);
    const f32x4 zero = {0.f, 0.f, 0.f, 0.f};
    float s0 = 0.f, s1 = 0.f, s2 = 0.f, s3 = 0.f;

    for (int ib = 0; ib < NPIX; ib += 64) {
        #pragma unroll
        for (int nt = 0; nt < 4; ++nt) {
            const bf16x8 qf = *reinterpret_cast<const bf16x8*>(
                &qb[(size_t)(ib + 16 * nt + lr) * CATT + lg * 8]);
            const f32x4 d = __builtin_amdgcn_mfma_f32_16x16x32_bf16(kfrag, qf, zero, 0, 0, 0);
            s0 += __builtin_amdgcn_exp2f(d[0]);
            s1 += __builtin_amdgcn_exp2f(d[1]);
            s2 += __builtin_amdgcn_exp2f(d[2]);
            s3 += __builtin_amdgcn_exp2f(d[3]);
        }
    }
    #pragma unroll
    for (int m = 1; m < 16; m <<= 1) {
        s0 += __shfl_xor(s0, m); s1 += __shfl_xor(s1, m);
        s2 += __shfl_xor(s2, m); s3 += __shfl_xor(s3, m);
    }
    if (lr == 0) {
        float4 o;
        o.x = 1.0f / s0; o.y = 1.0f / s1; o.z = 1.0f / s2; o.w = 1.0f / s3;
        *reinterpret_cast<float4*>(&rs[(size_t)b * NPIX + jblk + 16 * w + (lg << 2)]) = o;
    }
}

// ---------------------------------------------------------------------------
// K3: v projection -> vt[b][c][n] = bf16( gamma * rs[n] * (Wv x + bv) )
// grid (NPIX/128, CIN/32, NBATCH), block 256.
// ---------------------------------------------------------------------------
__global__ __launch_bounds__(256, 2)
void proj_v_kernel(const float* __restrict__ Wv, const float* __restrict__ bv,
                   const float* __restrict__ x, const float* __restrict__ rs,
                   const float* __restrict__ gamma, unsigned short* __restrict__ vt)
{
    __shared__ float sW[32][33];
    __shared__ float sX[32][128];
    const int t = threadIdx.x;
    const int nblk = blockIdx.x * 128;
    const int oblk = blockIdx.y * 32;
    const int b = blockIdx.z;
    const float* xb = x + (size_t)b * CIN * NPIX;
    const int tx = t & 31, ty = t >> 5;
    float acc[4][4] = {};

    for (int c0 = 0; c0 < CIN; c0 += 32) {
        __syncthreads();
        {
            const int r = t >> 3, c4 = (t & 7) << 2;
            const float4 w4 = *reinterpret_cast<const float4*>(&Wv[(size_t)(oblk + r) * CIN + c0 + c4]);
            sW[r][c4] = w4.x; sW[r][c4+1] = w4.y; sW[r][c4+2] = w4.z; sW[r][c4+3] = w4.w;
        }
        #pragma unroll
        for (int rr = 0; rr < 4; ++rr) {
            const int r = (t >> 5) + (rr << 3);
            const int c4 = (t & 31) << 2;
            *reinterpret_cast<float4*>(&sX[r][c4]) =
                *reinterpret_cast<const float4*>(&xb[(size_t)(c0 + r) * NPIX + nblk + c4]);
        }
        __syncthreads();
        #pragma unroll
        for (int kk = 0; kk < 32; ++kk) {
            float wv[4];
            #pragma unroll
            for (int oo = 0; oo < 4; ++oo) wv[oo] = sW[(ty << 2) + oo][kk];
            const float4 xx = *reinterpret_cast<const float4*>(&sX[kk][tx << 2]);
            const float xv[4] = {xx.x, xx.y, xx.z, xx.w};
            #pragma unroll
            for (int oo = 0; oo < 4; ++oo)
                #pragma unroll
                for (int nn = 0; nn < 4; ++nn)
                    acc[oo][nn] = fmaf(wv[oo], xv[nn], acc[oo][nn]);
        }
    }
    const float gv = gamma[0];
    const float4 rs4 = *reinterpret_cast<const float4*>(&rs[(size_t)b * NPIX + nblk + (tx << 2)]);
    #pragma unroll
    for (int oo = 0; oo < 4; ++oo) {
        const int c = oblk + (ty << 2) + oo;
        const float bb = bv[c];
        ushort4 u;
        u.x = f2bf_rne(gv * rs4.x * (acc[oo][0] + bb));
        u.y = f2bf_rne(gv * rs4.y * (acc[oo][1] + bb));
        u.z = f2bf_rne(gv * rs4.z * (acc[oo][2] + bb));
        u.w = f2bf_rne(gv * rs4.w * (acc[oo][3] + bb));
        *reinterpret_cast<ushort4*>(&vt[((size_t)b * CIN + c) * NPIX + nblk + (tx << 2)]) = u;
    }
}

// ---------------------------------------------------------------------------
// K4: fused E^T -> exp2 -> PV, all MFMA.
// Block: 32 i x 256 c, 4 waves (wave w: E j-tile 16w; PV c in [64w,64w+64)).
// P round-trips through XOR-swizzled LDS (write D-layout, read B-layout).
// grid 512 (XCD-swizzled so each XCD's L2 caches one batch's vt).
// ---------------------------------------------------------------------------
__global__ __launch_bounds__(256, 2)
void out_kernel(const unsigned short* __restrict__ qt,
                const unsigned short* __restrict__ kt,
                const unsigned short* __restrict__ vt,
                const float* __restrict__ x, float* __restrict__ out)
{
    __shared__ unsigned short sP[2][32 * 64];   // [i][j] bf16, 128B rows, XOR-swizzled
    const int n = blockIdx.x;
    const int b = (n & 7) >> 1;
    const int it = ((n >> 3) << 1) + (n & 1);
    const int iblk = it * 32;
    const int t = threadIdx.x, w = t >> 6, l = t & 63, lr = l & 15, lg = l >> 4;
    const unsigned short* qb = qt + (size_t)b * NPIX * CATT;
    const unsigned short* kb = kt + (size_t)b * NPIX * CATT;
    const unsigned short* vb = vt + (size_t)b * CIN * NPIX;
    const f32x4 zero = {0.f, 0.f, 0.f, 0.f};

    bf16x8 qfrag[2];
    #pragma unroll
    for (int nt = 0; nt < 2; ++nt)
        qfrag[nt] = *reinterpret_cast<const bf16x8*>(
            &qb[(size_t)(iblk + 16 * nt + lr) * CATT + lg * 8]);

    f32x4 acc[4][2] = {};

    for (int jb = 0; jb < 64; ++jb) {
        const int jblk = jb * 64;
        unsigned short* sp = &sP[jb & 1][0];

        const bf16x8 kfrag = *reinterpret_cast<const bf16x8*>(
            &kb[(size_t)(jblk + 16 * w + lr) * CATT + lg * 8]);

        bf16x8 vfrag[4][2];
        #pragma unroll
        for (int mt = 0; mt < 4; ++mt)
            #pragma unroll
            for (int kk = 0; kk < 2; ++kk)
                vfrag[mt][kk] = *reinterpret_cast<const bf16x8*>(
                    &vb[(size_t)(64 * w + 16 * mt + lr) * NPIX + jblk + kk * 32 + lg * 8]);

        f32x4 e[2];
        e[0] = __builtin_amdgcn_mfma_f32_16x16x32_bf16(kfrag, qfrag[0], zero, 0, 0, 0);
        e[1] = __builtin_amdgcn_mfma_f32_16x16x32_bf16(kfrag, qfrag[1], zero, 0, 0, 0);

        #pragma unroll
        for (int nt = 0; nt < 2; ++nt) {
            const float p0 = __builtin_amdgcn_exp2f(e[nt][0]);
            const float p1 = __builtin_amdgcn_exp2f(e[nt][1]);
            const float p2 = __builtin_amdgcn_exp2f(e[nt][2]);
            const float p3 = __builtin_amdgcn_exp2f(e[nt][3]);
            unsigned w0, w1;
            asm("v_cvt_pk_bf16_f32 %0, %1, %2" : "=v"(w0) : "v"(p0), "v"(p1));
            asm("v_cvt_pk_bf16_f32 %0, %1, %2" : "=v"(w1) : "v"(p2), "v"(p3));
            const int i_loc = 16 * nt + lr;
            int byte = i_loc * 128 + (16 * w + (lg << 2)) * 2;
            byte ^= (i_loc & 7) << 4;
            *reinterpret_cast<uint2*>(reinterpret_cast<char*>(sp) + byte) = make_uint2(w0, w1);
        }
        __syncthreads();

        #pragma unroll
        for (int kk = 0; kk < 2; ++kk) {
            bf16x8 pf[2];
            #pragma unroll
            for (int nt = 0; nt < 2; ++nt) {
                const int i_loc = 16 * nt + lr;
                int byte = i_loc * 128 + (kk * 32 + lg * 8) * 2;
                byte ^= (i_loc & 7) << 4;
                pf[nt] = *reinterpret_cast<const bf16x8*>(reinterpret_cast<char*>(sp) + byte);
            }
            #pragma unroll
            for (int mt = 0; mt < 4; ++mt) {
                acc[mt][0] = __builtin_amdgcn_mfma_f32_16x16x32_bf16(vfrag[mt][kk], pf[0], acc[mt][0], 0, 0, 0);
                acc[mt][1] = __builtin_amdgcn_mfma_f32_16x16x32_bf16(vfrag[mt][kk], pf[1], acc[mt][1], 0, 0, 0);
            }
        }
    }

    const float* xb = x + (size_t)b * CIN * NPIX;
    float* ob = out + (size_t)b * CIN * NPIX;
    #pragma unroll
    for (int mt = 0; mt < 4; ++mt)
        #pragma unroll
        for (int nt = 0; nt < 2; ++nt)
            #pragma unroll
            for (int r = 0; r < 4; ++r) {
                const int c = 64 * w + 16 * mt + (lg << 2) + r;
                const size_t idx = (size_t)c * NPIX + iblk + 16 * nt + lr;
                ob[idx] = acc[mt][nt][r] + xb[idx];
            }
}

// ---------------------------------------------------------------------------
extern "C" void kernel_launch(void* const* d_in, const int* in_sizes, int n_in,
                              void* d_out, int out_size, void* d_ws, size_t ws_size,
                              hipStream_t stream)
{
    const float* x     = (const float*)d_in[0];
    const float* Wq    = (const float*)d_in[1];
    const float* bq    = (const float*)d_in[2];
    const float* Wk    = (const float*)d_in[3];
    const float* bk    = (const float*)d_in[4];
    const float* Wv    = (const float*)d_in[5];
    const float* bv    = (const float*)d_in[6];
    const float* gamma = (const float*)d_in[7];
    float* out = (float*)d_out;

    // workspace: qt | kt (bf16 [b][n][32]) | vt (bf16 [b][c][n]) | rs (f32)  ~10.5 MB
    unsigned short* qt = (unsigned short*)d_ws;
    unsigned short* kt = qt + (size_t)NBATCH * NPIX * CATT;
    unsigned short* vt = kt + (size_t)NBATCH * NPIX * CATT;
    float* rsw = (float*)(vt + (size_t)NBATCH * CIN * NPIX);

    proj_qk_kernel<<<dim3(NPIX / 128, NBATCH), 256, 0, stream>>>(Wq, bq, Wk, bk, x, qt, kt);
    stats_kernel<<<dim3((NPIX / 64) * NBATCH), 256, 0, stream>>>(qt, kt, rsw);
    proj_v_kernel<<<dim3(NPIX / 128, CIN / 32, NBATCH), 256, 0, stream>>>(Wv, bv, x, rsw, gamma, vt);
    out_kernel<<<dim3((NPIX / 32) * NBATCH), 256, 0, stream>>>(qt, kt, vt, x, out);
}

// Round 4
// 148.263 us; speedup vs baseline: 5.3639x; 1.3527x over previous
//
#include <hip/hip_runtime.h>

#define NBATCH 4
#define CIN 256
#define CATT 32
#define NPIX 4096

static constexpr float LOG2E_F = 1.4426950408889634f;

typedef __attribute__((ext_vector_type(8))) short bf16x8;
typedef __attribute__((ext_vector_type(4))) float f32x4;

__device__ __forceinline__ unsigned short f2bf_rne(float f) {
    unsigned u = __builtin_bit_cast(unsigned, f);
    return (unsigned short)((u + 0x7fffu + ((u >> 16) & 1u)) >> 16);
}

// ---------------------------------------------------------------------------
// K1: fused q/k projection -> transposed bf16 outputs qt[b][n][32], kt[b][n][32]
// q gets LOG2E folded.  grid (NPIX/128, NBATCH), block 256.
// ---------------------------------------------------------------------------
__global__ __launch_bounds__(256, 2)
void proj_qk_kernel(const float* __restrict__ Wq, const float* __restrict__ bq,
                    const float* __restrict__ Wk, const float* __restrict__ bk,
                    const float* __restrict__ x,
                    unsigned short* __restrict__ qt, unsigned short* __restrict__ kt)
{
    __shared__ float sWq[32][33];
    __shared__ float sWk[32][33];
    __shared__ float sX[32][128];
    const int t = threadIdx.x;
    const int nblk = blockIdx.x * 128;
    const int b = blockIdx.y;
    const float* xb = x + (size_t)b * CIN * NPIX;
    const int tx = t & 31, ty = t >> 5;
    float aq[4][4] = {}, ak[4][4] = {};

    for (int c0 = 0; c0 < CIN; c0 += 32) {
        __syncthreads();
        {
            const int r = t >> 3, c4 = (t & 7) << 2;
            float4 w4 = *reinterpret_cast<const float4*>(&Wq[(size_t)r * CIN + c0 + c4]);
            sWq[r][c4] = w4.x; sWq[r][c4+1] = w4.y; sWq[r][c4+2] = w4.z; sWq[r][c4+3] = w4.w;
            w4 = *reinterpret_cast<const float4*>(&Wk[(size_t)r * CIN + c0 + c4]);
            sWk[r][c4] = w4.x; sWk[r][c4+1] = w4.y; sWk[r][c4+2] = w4.z; sWk[r][c4+3] = w4.w;
        }
        #pragma unroll
        for (int rr = 0; rr < 4; ++rr) {
            const int r = (t >> 5) + (rr << 3);
            const int c4 = (t & 31) << 2;
            *reinterpret_cast<float4*>(&sX[r][c4]) =
                *reinterpret_cast<const float4*>(&xb[(size_t)(c0 + r) * NPIX + nblk + c4]);
        }
        __syncthreads();
        #pragma unroll
        for (int kk = 0; kk < 32; ++kk) {
            float wq[4], wk[4];
            #pragma unroll
            for (int oo = 0; oo < 4; ++oo) { wq[oo] = sWq[(ty << 2) + oo][kk]; wk[oo] = sWk[(ty << 2) + oo][kk]; }
            const float4 xx = *reinterpret_cast<const float4*>(&sX[kk][tx << 2]);
            const float xv[4] = {xx.x, xx.y, xx.z, xx.w};
            #pragma unroll
            for (int oo = 0; oo < 4; ++oo)
                #pragma unroll
                for (int nn = 0; nn < 4; ++nn) {
                    aq[oo][nn] = fmaf(wq[oo], xv[nn], aq[oo][nn]);
                    ak[oo][nn] = fmaf(wk[oo], xv[nn], ak[oo][nn]);
                }
        }
    }
    float bqv[4], bkv[4];
    #pragma unroll
    for (int oo = 0; oo < 4; ++oo) { bqv[oo] = bq[(ty << 2) + oo]; bkv[oo] = bk[(ty << 2) + oo]; }
    #pragma unroll
    for (int nn = 0; nn < 4; ++nn) {
        const int n = nblk + (tx << 2) + nn;
        ushort4 uq, uk;
        uq.x = f2bf_rne(LOG2E_F * (aq[0][nn] + bqv[0]));
        uq.y = f2bf_rne(LOG2E_F * (aq[1][nn] + bqv[1]));
        uq.z = f2bf_rne(LOG2E_F * (aq[2][nn] + bqv[2]));
        uq.w = f2bf_rne(LOG2E_F * (aq[3][nn] + bqv[3]));
        uk.x = f2bf_rne(ak[0][nn] + bkv[0]);
        uk.y = f2bf_rne(ak[1][nn] + bkv[1]);
        uk.z = f2bf_rne(ak[2][nn] + bkv[2]);
        uk.w = f2bf_rne(ak[3][nn] + bkv[3]);
        const size_t base = ((size_t)b * NPIX + n) * CATT + (ty << 2);
        *reinterpret_cast<ushort4*>(&qt[base]) = uq;
        *reinterpret_cast<ushort4*>(&kt[base]) = uk;
    }
}

// ---------------------------------------------------------------------------
// K2: stats via MFMA, software-pipelined.
// rs[b][j] = 1 / sum_i exp2(E^T[j,i]).
// grid 512: b = n&3 (XCD-resident), jt = n>>2 (0..127), j-tile 32.
// 4 waves: wave w -> j-slice (w&1)*16, i-half (w>>1)*2048.
// ---------------------------------------------------------------------------
__global__ __launch_bounds__(256, 2)
void stats_kernel(const unsigned short* __restrict__ qt,
                  const unsigned short* __restrict__ kt, float* __restrict__ rs)
{
    __shared__ float sred[4][16];
    const int n = blockIdx.x;
    const int b = n & 3;
    const int jblk = (n >> 2) * 32;
    const int t = threadIdx.x, w = t >> 6, l = t & 63, lr = l & 15, lg = l >> 4;
    const int jsl = w & 1;
    const int ih = w >> 1;
    const unsigned short* qb = qt + (size_t)b * NPIX * CATT;
    const unsigned short* kb = kt + (size_t)b * NPIX * CATT;

    const bf16x8 kfrag = *reinterpret_cast<const bf16x8*>(
        &kb[(size_t)(jblk + 16 * jsl + lr) * CATT + lg * 8]);
    const f32x4 zero = {0.f, 0.f, 0.f, 0.f};
    const unsigned short* qp = qb + (size_t)(ih * 2048 + lr) * CATT + lg * 8;

    float s0 = 0.f, s1 = 0.f, s2 = 0.f, s3 = 0.f;
    bf16x8 qc0 = *reinterpret_cast<const bf16x8*>(qp);
    bf16x8 qc1 = *reinterpret_cast<const bf16x8*>(qp + 16 * CATT);
    bf16x8 qc2 = *reinterpret_cast<const bf16x8*>(qp + 32 * CATT);
    bf16x8 qc3 = *reinterpret_cast<const bf16x8*>(qp + 48 * CATT);

    for (int ib = 0; ib < 2048; ib += 64) {
        bf16x8 qn0, qn1, qn2, qn3;
        const bool more = (ib + 64) < 2048;
        if (more) {
            const unsigned short* q2 = qp + (size_t)(ib + 64) * CATT;
            qn0 = *reinterpret_cast<const bf16x8*>(q2);
            qn1 = *reinterpret_cast<const bf16x8*>(q2 + 16 * CATT);
            qn2 = *reinterpret_cast<const bf16x8*>(q2 + 32 * CATT);
            qn3 = *reinterpret_cast<const bf16x8*>(q2 + 48 * CATT);
        }
        f32x4 d;
        d = __builtin_amdgcn_mfma_f32_16x16x32_bf16(kfrag, qc0, zero, 0, 0, 0);
        s0 += __builtin_amdgcn_exp2f(d[0]); s1 += __builtin_amdgcn_exp2f(d[1]);
        s2 += __builtin_amdgcn_exp2f(d[2]); s3 += __builtin_amdgcn_exp2f(d[3]);
        d = __builtin_amdgcn_mfma_f32_16x16x32_bf16(kfrag, qc1, zero, 0, 0, 0);
        s0 += __builtin_amdgcn_exp2f(d[0]); s1 += __builtin_amdgcn_exp2f(d[1]);
        s2 += __builtin_amdgcn_exp2f(d[2]); s3 += __builtin_amdgcn_exp2f(d[3]);
        d = __builtin_amdgcn_mfma_f32_16x16x32_bf16(kfrag, qc2, zero, 0, 0, 0);
        s0 += __builtin_amdgcn_exp2f(d[0]); s1 += __builtin_amdgcn_exp2f(d[1]);
        s2 += __builtin_amdgcn_exp2f(d[2]); s3 += __builtin_amdgcn_exp2f(d[3]);
        d = __builtin_amdgcn_mfma_f32_16x16x32_bf16(kfrag, qc3, zero, 0, 0, 0);
        s0 += __builtin_amdgcn_exp2f(d[0]); s1 += __builtin_amdgcn_exp2f(d[1]);
        s2 += __builtin_amdgcn_exp2f(d[2]); s3 += __builtin_amdgcn_exp2f(d[3]);
        if (more) { qc0 = qn0; qc1 = qn1; qc2 = qn2; qc3 = qn3; }
    }
    #pragma unroll
    for (int m = 1; m < 16; m <<= 1) {
        s0 += __shfl_xor(s0, m); s1 += __shfl_xor(s1, m);
        s2 += __shfl_xor(s2, m); s3 += __shfl_xor(s3, m);
    }
    if (lr == 0) {
        sred[w][(lg << 2) + 0] = s0;
        sred[w][(lg << 2) + 1] = s1;
        sred[w][(lg << 2) + 2] = s2;
        sred[w][(lg << 2) + 3] = s3;
    }
    __syncthreads();
    if (t < 32) {
        const int j16 = t & 15, js = t >> 4;
        const float s = sred[js][j16] + sred[js + 2][j16];
        rs[(size_t)b * NPIX + jblk + t] = 1.0f / s;
    }
}

// ---------------------------------------------------------------------------
// K3: v projection -> vt[b][c][n] = bf16( gamma * rs[n] * (Wv x + bv) )
// grid (NPIX/128, CIN/32, NBATCH), block 256.
// ---------------------------------------------------------------------------
__global__ __launch_bounds__(256, 2)
void proj_v_kernel(const float* __restrict__ Wv, const float* __restrict__ bv,
                   const float* __restrict__ x, const float* __restrict__ rs,
                   const float* __restrict__ gamma, unsigned short* __restrict__ vt)
{
    __shared__ float sW[32][33];
    __shared__ float sX[32][128];
    const int t = threadIdx.x;
    const int nblk = blockIdx.x * 128;
    const int oblk = blockIdx.y * 32;
    const int b = blockIdx.z;
    const float* xb = x + (size_t)b * CIN * NPIX;
    const int tx = t & 31, ty = t >> 5;
    float acc[4][4] = {};

    for (int c0 = 0; c0 < CIN; c0 += 32) {
        __syncthreads();
        {
            const int r = t >> 3, c4 = (t & 7) << 2;
            const float4 w4 = *reinterpret_cast<const float4*>(&Wv[(size_t)(oblk + r) * CIN + c0 + c4]);
            sW[r][c4] = w4.x; sW[r][c4+1] = w4.y; sW[r][c4+2] = w4.z; sW[r][c4+3] = w4.w;
        }
        #pragma unroll
        for (int rr = 0; rr < 4; ++rr) {
            const int r = (t >> 5) + (rr << 3);
            const int c4 = (t & 31) << 2;
            *reinterpret_cast<float4*>(&sX[r][c4]) =
                *reinterpret_cast<const float4*>(&xb[(size_t)(c0 + r) * NPIX + nblk + c4]);
        }
        __syncthreads();
        #pragma unroll
        for (int kk = 0; kk < 32; ++kk) {
            float wv[4];
            #pragma unroll
            for (int oo = 0; oo < 4; ++oo) wv[oo] = sW[(ty << 2) + oo][kk];
            const float4 xx = *reinterpret_cast<const float4*>(&sX[kk][tx << 2]);
            const float xv[4] = {xx.x, xx.y, xx.z, xx.w};
            #pragma unroll
            for (int oo = 0; oo < 4; ++oo)
                #pragma unroll
                for (int nn = 0; nn < 4; ++nn)
                    acc[oo][nn] = fmaf(wv[oo], xv[nn], acc[oo][nn]);
        }
    }
    const float gv = gamma[0];
    const float4 rs4 = *reinterpret_cast<const float4*>(&rs[(size_t)b * NPIX + nblk + (tx << 2)]);
    #pragma unroll
    for (int oo = 0; oo < 4; ++oo) {
        const int c = oblk + (ty << 2) + oo;
        const float bb = bv[c];
        ushort4 u;
        u.x = f2bf_rne(gv * rs4.x * (acc[oo][0] + bb));
        u.y = f2bf_rne(gv * rs4.y * (acc[oo][1] + bb));
        u.z = f2bf_rne(gv * rs4.z * (acc[oo][2] + bb));
        u.w = f2bf_rne(gv * rs4.w * (acc[oo][3] + bb));
        *reinterpret_cast<ushort4*>(&vt[((size_t)b * CIN + c) * NPIX + nblk + (tx << 2)]) = u;
    }
}

// ---------------------------------------------------------------------------
// K4: fused E^T -> exp2 -> PV, software-pipelined.
// Block: 64 i x 128 c, 4 waves. Wave w: E j-slice [16w,16w+16); PV c-slice
// [cblk+32w, cblk+32w+32). grid 512: b = n&3, ch = (n>>2)&1, it = n>>3.
// P round-trips through XOR-swizzled double-buffered LDS (8KB x2).
// Swizzle note: the XOR term (lr&7)<<4 lives in byte bits [6:4]; it must be
// XORed against the FULL column byte (incl. the kk*64 bit-6 term) — adding
// kk*64 after the XOR carries into bit 7 (wrong row / OOB). (R3 bug.)
// ---------------------------------------------------------------------------
__global__ __launch_bounds__(256, 2)
void out_kernel(const unsigned short* __restrict__ qt,
                const unsigned short* __restrict__ kt,
                const unsigned short* __restrict__ vt,
                const float* __restrict__ x, float* __restrict__ out)
{
    __shared__ unsigned short sP[2][64 * 64];   // [i][j] bf16, 128B rows, swizzled
    const int n = blockIdx.x;
    const int b = n & 3;
    const int rest = n >> 2;
    const int ch = rest & 1;
    const int it = rest >> 1;          // 0..63
    const int iblk = it * 64;
    const int cblk = ch * 128;
    const int t = threadIdx.x, w = t >> 6, l = t & 63, lr = l & 15, lg = l >> 4;
    const unsigned short* qb = qt + (size_t)b * NPIX * CATT;
    const unsigned short* kb = kt + (size_t)b * NPIX * CATT;
    const unsigned short* vb = vt + (size_t)b * CIN * NPIX;
    const f32x4 zero = {0.f, 0.f, 0.f, 0.f};

    bf16x8 qfrag[4];
    #pragma unroll
    for (int nt = 0; nt < 4; ++nt)
        qfrag[nt] = *reinterpret_cast<const bf16x8*>(
            &qb[(size_t)(iblk + 16 * nt + lr) * CATT + lg * 8]);

    const unsigned short* kp = kb + (size_t)(16 * w + lr) * CATT + lg * 8;
    const unsigned short* vp = vb + (size_t)(cblk + 32 * w + lr) * NPIX + lg * 8;

    const int swz = (lr & 7) << 4;
    const int wb0 = lr * 128 + (((16 * w + 4 * lg) * 2) ^ swz);   // write col: uint2
    const int rb_col0 = (0 * 64 + 16 * lg) ^ swz;                 // read col, kk=0
    const int rb_col1 = (1 * 64 + 16 * lg) ^ swz;                 // read col, kk=1

    f32x4 acc[2][4] = {};

    bf16x8 kf   = *reinterpret_cast<const bf16x8*>(kp);
    bf16x8 vf00 = *reinterpret_cast<const bf16x8*>(vp);
    bf16x8 vf01 = *reinterpret_cast<const bf16x8*>(vp + 32);
    bf16x8 vf10 = *reinterpret_cast<const bf16x8*>(vp + 16 * (size_t)NPIX);
    bf16x8 vf11 = *reinterpret_cast<const bf16x8*>(vp + 16 * (size_t)NPIX + 32);

    for (int jb = 0; jb < NPIX / 64; ++jb) {
        bf16x8 kf_n, vn00, vn01, vn10, vn11;
        const bool more = jb < NPIX / 64 - 1;
        if (more) {
            const unsigned short* kp2 = kp + (size_t)(jb + 1) * 64 * CATT;
            const unsigned short* vp2 = vp + (size_t)(jb + 1) * 64;
            kf_n = *reinterpret_cast<const bf16x8*>(kp2);
            vn00 = *reinterpret_cast<const bf16x8*>(vp2);
            vn01 = *reinterpret_cast<const bf16x8*>(vp2 + 32);
            vn10 = *reinterpret_cast<const bf16x8*>(vp2 + 16 * (size_t)NPIX);
            vn11 = *reinterpret_cast<const bf16x8*>(vp2 + 16 * (size_t)NPIX + 32);
        }
        char* sp = reinterpret_cast<char*>(&sP[jb & 1][0]);
        // ---- E phase: 4 MFMA -> 16 exp2 -> 8 cvt_pk -> LDS write
        #pragma unroll
        for (int nt = 0; nt < 4; ++nt) {
            const f32x4 e = __builtin_amdgcn_mfma_f32_16x16x32_bf16(kf, qfrag[nt], zero, 0, 0, 0);
            const float p0 = __builtin_amdgcn_exp2f(e[0]);
            const float p1 = __builtin_amdgcn_exp2f(e[1]);
            const float p2 = __builtin_amdgcn_exp2f(e[2]);
            const float p3 = __builtin_amdgcn_exp2f(e[3]);
            unsigned w0, w1;
            asm("v_cvt_pk_bf16_f32 %0, %1, %2" : "=v"(w0) : "v"(p0), "v"(p1));
            asm("v_cvt_pk_bf16_f32 %0, %1, %2" : "=v"(w1) : "v"(p2), "v"(p3));
            *reinterpret_cast<uint2*>(sp + wb0 + nt * 2048) = make_uint2(w0, w1);
        }
        __syncthreads();
        // ---- PV phase: 8 LDS reads + 16 MFMA
        #pragma unroll
        for (int kk = 0; kk < 2; ++kk) {
            const int rbc = (kk == 0) ? rb_col0 : rb_col1;
            bf16x8 pf[4];
            #pragma unroll
            for (int nt = 0; nt < 4; ++nt)
                pf[nt] = *reinterpret_cast<const bf16x8*>(sp + lr * 128 + nt * 2048 + rbc);
            __builtin_amdgcn_s_setprio(1);
            #pragma unroll
            for (int nt = 0; nt < 4; ++nt) {
                acc[0][nt] = __builtin_amdgcn_mfma_f32_16x16x32_bf16(
                    kk == 0 ? vf00 : vf01, pf[nt], acc[0][nt], 0, 0, 0);
                acc[1][nt] = __builtin_amdgcn_mfma_f32_16x16x32_bf16(
                    kk == 0 ? vf10 : vf11, pf[nt], acc[1][nt], 0, 0, 0);
            }
            __builtin_amdgcn_s_setprio(0);
        }
        if (more) { kf = kf_n; vf00 = vn00; vf01 = vn01; vf10 = vn10; vf11 = vn11; }
    }

    const float* xb = x + (size_t)b * CIN * NPIX;
    float* ob = out + (size_t)b * CIN * NPIX;
    #pragma unroll
    for (int mt = 0; mt < 2; ++mt)
        #pragma unroll
        for (int nt = 0; nt < 4; ++nt)
            #pragma unroll
            for (int r = 0; r < 4; ++r) {
                const int c = cblk + 32 * w + 16 * mt + (lg << 2) + r;
                const size_t idx = (size_t)c * NPIX + iblk + 16 * nt + lr;
                ob[idx] = acc[mt][nt][r] + xb[idx];
            }
}

// ---------------------------------------------------------------------------
extern "C" void kernel_launch(void* const* d_in, const int* in_sizes, int n_in,
                              void* d_out, int out_size, void* d_ws, size_t ws_size,
                              hipStream_t stream)
{
    const float* x     = (const float*)d_in[0];
    const float* Wq    = (const float*)d_in[1];
    const float* bq    = (const float*)d_in[2];
    const float* Wk    = (const float*)d_in[3];
    const float* bk    = (const float*)d_in[4];
    const float* Wv    = (const float*)d_in[5];
    const float* bv    = (const float*)d_in[6];
    const float* gamma = (const float*)d_in[7];
    float* out = (float*)d_out;

    // workspace: qt | kt (bf16 [b][n][32]) | vt (bf16 [b][c][n]) | rs (f32)  ~10.5 MB
    unsigned short* qt = (unsigned short*)d_ws;
    unsigned short* kt = qt + (size_t)NBATCH * NPIX * CATT;
    unsigned short* vt = kt + (size_t)NBATCH * NPIX * CATT;
    float* rsw = (float*)(vt + (size_t)NBATCH * CIN * NPIX);

    proj_qk_kernel<<<dim3(NPIX / 128, NBATCH), 256, 0, stream>>>(Wq, bq, Wk, bk, x, qt, kt);
    stats_kernel<<<dim3((NPIX / 32) * NBATCH), 256, 0, stream>>>(qt, kt, rsw);
    proj_v_kernel<<<dim3(NPIX / 128, CIN / 32, NBATCH), 256, 0, stream>>>(Wv, bv, x, rsw, gamma, vt);
    out_kernel<<<dim3((NPIX / 64) * 2 * NBATCH), 256, 0, stream>>>(qt, kt, vt, x, out);
}

// Round 5
// 134.192 us; speedup vs baseline: 5.9264x; 1.1049x over previous
//
#include <hip/hip_runtime.h>

#define NBATCH 4
#define CIN 256
#define CATT 32
#define NPIX 4096

static constexpr float LOG2E_F = 1.4426950408889634f;

typedef __attribute__((ext_vector_type(8))) short bf16x8;
typedef __attribute__((ext_vector_type(4))) float f32x4;

__device__ __forceinline__ unsigned short f2bf_rne(float f) {
    unsigned u = __builtin_bit_cast(unsigned, f);
    return (unsigned short)((u + 0x7fffu + ((u >> 16) & 1u)) >> 16);
}
__device__ __forceinline__ float bf2f(unsigned short h) {
    unsigned u = (unsigned)h << 16;
    return __builtin_bit_cast(float, u);
}
// 8 consecutive f32 -> bf16 hi + bf16 lo fragments (hi+lo ~ 2^-17 rel error)
__device__ __forceinline__ void split8(const float* p, bf16x8& hi, bf16x8& lo) {
    const float4 a = *reinterpret_cast<const float4*>(p);
    const float4 b = *reinterpret_cast<const float4*>(p + 4);
    const float f[8] = {a.x, a.y, a.z, a.w, b.x, b.y, b.z, b.w};
    #pragma unroll
    for (int e = 0; e < 8; ++e) {
        const unsigned short h = f2bf_rne(f[e]);
        hi[e] = (short)h;
        lo[e] = (short)f2bf_rne(f[e] - bf2f(h));
    }
}
__device__ __forceinline__ bf16x8 cvt8(const float* p) {
    const float4 a = *reinterpret_cast<const float4*>(p);
    const float4 b = *reinterpret_cast<const float4*>(p + 4);
    const float f[8] = {a.x, a.y, a.z, a.w, b.x, b.y, b.z, b.w};
    bf16x8 r;
    #pragma unroll
    for (int e = 0; e < 8; ++e) r[e] = (short)f2bf_rne(f[e]);
    return r;
}

// ---------------------------------------------------------------------------
// K0: x[b][c][n] f32 -> xT[b][n][256] bf16 (LDS tile transpose 64c x 64n)
// grid (64, 4, 4), block 256.
// ---------------------------------------------------------------------------
__global__ __launch_bounds__(256, 2)
void transpose_kernel(const float* __restrict__ x, unsigned short* __restrict__ xT)
{
    __shared__ unsigned short sT[64][68];
    const int t = threadIdx.x;
    const int nblk = blockIdx.x * 64;
    const int cblk = blockIdx.y * 64;
    const int b = blockIdx.z;
    const float* xb = x + ((size_t)b * CIN + cblk) * NPIX + nblk;
    const int lc = t >> 2, ln = (t & 3) << 4;
    #pragma unroll
    for (int u = 0; u < 4; ++u) {
        const float4 v = *reinterpret_cast<const float4*>(&xb[(size_t)lc * NPIX + ln + 4 * u]);
        sT[ln + 4 * u + 0][lc] = f2bf_rne(v.x);
        sT[ln + 4 * u + 1][lc] = f2bf_rne(v.y);
        sT[ln + 4 * u + 2][lc] = f2bf_rne(v.z);
        sT[ln + 4 * u + 3][lc] = f2bf_rne(v.w);
    }
    __syncthreads();
    const int rn = t >> 2, cs = (t & 3) << 4;
    const uint2 d0 = *reinterpret_cast<const uint2*>(&sT[rn][cs + 0]);
    const uint2 d1 = *reinterpret_cast<const uint2*>(&sT[rn][cs + 4]);
    const uint2 d2 = *reinterpret_cast<const uint2*>(&sT[rn][cs + 8]);
    const uint2 d3 = *reinterpret_cast<const uint2*>(&sT[rn][cs + 12]);
    unsigned short* dst = xT + ((size_t)b * NPIX + nblk + rn) * CIN + cblk + cs;
    *reinterpret_cast<uint4*>(dst)     = make_uint4(d0.x, d0.y, d1.x, d1.y);
    *reinterpret_cast<uint4*>(dst + 8) = make_uint4(d2.x, d2.y, d3.x, d3.y);
}

// ---------------------------------------------------------------------------
// K1: q/k projection via MFMA, W split hi/lo (bf16) for precision.
// A = W (m=a, k=c), B = xT (k=c, n=n).  D: col=lr -> n, row=4lg+r -> a.
// Block 256 = 4 waves; wave w -> n-tile [n0, n0+16).  grid (64, 4).
// ---------------------------------------------------------------------------
__global__ __launch_bounds__(256, 2)
void proj_qk_kernel(const float* __restrict__ Wq, const float* __restrict__ bq,
                    const float* __restrict__ Wk, const float* __restrict__ bk,
                    const unsigned short* __restrict__ xT,
                    unsigned short* __restrict__ qt, unsigned short* __restrict__ kt)
{
    const int t = threadIdx.x, w = t >> 6, l = t & 63, lr = l & 15, lg = l >> 4;
    const int b = blockIdx.y;
    const int n0 = blockIdx.x * 64 + 16 * w;
    const unsigned short* xrow = xT + ((size_t)b * NPIX + n0 + lr) * CIN + lg * 8;
    f32x4 aq[2] = {{0.f,0.f,0.f,0.f},{0.f,0.f,0.f,0.f}};
    f32x4 ak2[2] = {{0.f,0.f,0.f,0.f},{0.f,0.f,0.f,0.f}};
    #pragma unroll
    for (int ks = 0; ks < 8; ++ks) {
        const int ko = ks * 32 + lg * 8;
        const bf16x8 bx = *reinterpret_cast<const bf16x8*>(xrow + ks * 32);
        #pragma unroll
        for (int mt = 0; mt < 2; ++mt) {
            bf16x8 wh, wl;
            split8(&Wq[(size_t)(mt * 16 + lr) * CIN + ko], wh, wl);
            aq[mt] = __builtin_amdgcn_mfma_f32_16x16x32_bf16(wh, bx, aq[mt], 0, 0, 0);
            aq[mt] = __builtin_amdgcn_mfma_f32_16x16x32_bf16(wl, bx, aq[mt], 0, 0, 0);
            split8(&Wk[(size_t)(mt * 16 + lr) * CIN + ko], wh, wl);
            ak2[mt] = __builtin_amdgcn_mfma_f32_16x16x32_bf16(wh, bx, ak2[mt], 0, 0, 0);
            ak2[mt] = __builtin_amdgcn_mfma_f32_16x16x32_bf16(wl, bx, ak2[mt], 0, 0, 0);
        }
    }
    #pragma unroll
    for (int mt = 0; mt < 2; ++mt) {
        const float4 b4q = *reinterpret_cast<const float4*>(&bq[16 * mt + (lg << 2)]);
        const float4 b4k = *reinterpret_cast<const float4*>(&bk[16 * mt + (lg << 2)]);
        ushort4 uq, uk;
        uq.x = f2bf_rne(LOG2E_F * (aq[mt][0] + b4q.x));
        uq.y = f2bf_rne(LOG2E_F * (aq[mt][1] + b4q.y));
        uq.z = f2bf_rne(LOG2E_F * (aq[mt][2] + b4q.z));
        uq.w = f2bf_rne(LOG2E_F * (aq[mt][3] + b4q.w));
        uk.x = f2bf_rne(ak2[mt][0] + b4k.x);
        uk.y = f2bf_rne(ak2[mt][1] + b4k.y);
        uk.z = f2bf_rne(ak2[mt][2] + b4k.z);
        uk.w = f2bf_rne(ak2[mt][3] + b4k.w);
        const size_t base = ((size_t)b * NPIX + n0 + lr) * CATT + 16 * mt + (lg << 2);
        *reinterpret_cast<ushort4*>(&qt[base]) = uq;
        *reinterpret_cast<ushort4*>(&kt[base]) = uk;
    }
}

// ---------------------------------------------------------------------------
// K2: stats via MFMA, software-pipelined (unchanged from R4).
// ---------------------------------------------------------------------------
__global__ __launch_bounds__(256, 2)
void stats_kernel(const unsigned short* __restrict__ qt,
                  const unsigned short* __restrict__ kt, float* __restrict__ rs)
{
    __shared__ float sred[4][16];
    const int n = blockIdx.x;
    const int b = n & 3;
    const int jblk = (n >> 2) * 32;
    const int t = threadIdx.x, w = t >> 6, l = t & 63, lr = l & 15, lg = l >> 4;
    const int jsl = w & 1;
    const int ih = w >> 1;
    const unsigned short* qb = qt + (size_t)b * NPIX * CATT;
    const unsigned short* kb = kt + (size_t)b * NPIX * CATT;

    const bf16x8 kfrag = *reinterpret_cast<const bf16x8*>(
        &kb[(size_t)(jblk + 16 * jsl + lr) * CATT + lg * 8]);
    const f32x4 zero = {0.f, 0.f, 0.f, 0.f};
    const unsigned short* qp = qb + (size_t)(ih * 2048 + lr) * CATT + lg * 8;

    float s0 = 0.f, s1 = 0.f, s2 = 0.f, s3 = 0.f;
    bf16x8 qc0 = *reinterpret_cast<const bf16x8*>(qp);
    bf16x8 qc1 = *reinterpret_cast<const bf16x8*>(qp + 16 * CATT);
    bf16x8 qc2 = *reinterpret_cast<const bf16x8*>(qp + 32 * CATT);
    bf16x8 qc3 = *reinterpret_cast<const bf16x8*>(qp + 48 * CATT);

    for (int ib = 0; ib < 2048; ib += 64) {
        bf16x8 qn0, qn1, qn2, qn3;
        const bool more = (ib + 64) < 2048;
        if (more) {
            const unsigned short* q2 = qp + (size_t)(ib + 64) * CATT;
            qn0 = *reinterpret_cast<const bf16x8*>(q2);
            qn1 = *reinterpret_cast<const bf16x8*>(q2 + 16 * CATT);
            qn2 = *reinterpret_cast<const bf16x8*>(q2 + 32 * CATT);
            qn3 = *reinterpret_cast<const bf16x8*>(q2 + 48 * CATT);
        }
        f32x4 d;
        d = __builtin_amdgcn_mfma_f32_16x16x32_bf16(kfrag, qc0, zero, 0, 0, 0);
        s0 += __builtin_amdgcn_exp2f(d[0]); s1 += __builtin_amdgcn_exp2f(d[1]);
        s2 += __builtin_amdgcn_exp2f(d[2]); s3 += __builtin_amdgcn_exp2f(d[3]);
        d = __builtin_amdgcn_mfma_f32_16x16x32_bf16(kfrag, qc1, zero, 0, 0, 0);
        s0 += __builtin_amdgcn_exp2f(d[0]); s1 += __builtin_amdgcn_exp2f(d[1]);
        s2 += __builtin_amdgcn_exp2f(d[2]); s3 += __builtin_amdgcn_exp2f(d[3]);
        d = __builtin_amdgcn_mfma_f32_16x16x32_bf16(kfrag, qc2, zero, 0, 0, 0);
        s0 += __builtin_amdgcn_exp2f(d[0]); s1 += __builtin_amdgcn_exp2f(d[1]);
        s2 += __builtin_amdgcn_exp2f(d[2]); s3 += __builtin_amdgcn_exp2f(d[3]);
        d = __builtin_amdgcn_mfma_f32_16x16x32_bf16(kfrag, qc3, zero, 0, 0, 0);
        s0 += __builtin_amdgcn_exp2f(d[0]); s1 += __builtin_amdgcn_exp2f(d[1]);
        s2 += __builtin_amdgcn_exp2f(d[2]); s3 += __builtin_amdgcn_exp2f(d[3]);
        if (more) { qc0 = qn0; qc1 = qn1; qc2 = qn2; qc3 = qn3; }
    }
    #pragma unroll
    for (int m = 1; m < 16; m <<= 1) {
        s0 += __shfl_xor(s0, m); s1 += __shfl_xor(s1, m);
        s2 += __shfl_xor(s2, m); s3 += __shfl_xor(s3, m);
    }
    if (lr == 0) {
        sred[w][(lg << 2) + 0] = s0;
        sred[w][(lg << 2) + 1] = s1;
        sred[w][(lg << 2) + 2] = s2;
        sred[w][(lg << 2) + 3] = s3;
    }
    __syncthreads();
    if (t < 32) {
        const int j16 = t & 15, js = t >> 4;
        const float s = sred[js][j16] + sred[js + 2][j16];
        rs[(size_t)b * NPIX + jblk + t] = 1.0f / s;
    }
}

// ---------------------------------------------------------------------------
// K3: v projection via MFMA -> vt[b][c][n] = bf16(gamma * rs[n] * (Wv x + bv))
// A = xT (m=n_pix), B = Wv rows (k=c_in, n=c_out).
// D: col=lr -> c_out, row=4lg+r -> n_pix  => ushort4 writes along n.
// Block 256 = 4 waves; wave w -> c_out [64w,64w+64), n-tile 32. grid (128, 4).
// ---------------------------------------------------------------------------
__global__ __launch_bounds__(256, 2)
void proj_v_kernel(const float* __restrict__ Wv, const float* __restrict__ bv,
                   const unsigned short* __restrict__ xT, const float* __restrict__ rs,
                   const float* __restrict__ gamma, unsigned short* __restrict__ vt)
{
    const int t = threadIdx.x, w = t >> 6, l = t & 63, lr = l & 15, lg = l >> 4;
    const int b = blockIdx.y;
    const int n0 = blockIdx.x * 32;
    const int cb = 64 * w;
    const unsigned short* xa = xT + ((size_t)b * NPIX + n0) * CIN;
    f32x4 acc[2][4] = {};
    #pragma unroll
    for (int ks = 0; ks < 8; ++ks) {
        const int ko = ks * 32 + lg * 8;
        bf16x8 af[2];
        #pragma unroll
        for (int mt = 0; mt < 2; ++mt)
            af[mt] = *reinterpret_cast<const bf16x8*>(&xa[(size_t)(16 * mt + lr) * CIN + ko]);
        #pragma unroll
        for (int ct = 0; ct < 4; ++ct) {
            const bf16x8 wf = cvt8(&Wv[(size_t)(cb + 16 * ct + lr) * CIN + ko]);
            #pragma unroll
            for (int mt = 0; mt < 2; ++mt)
                acc[mt][ct] = __builtin_amdgcn_mfma_f32_16x16x32_bf16(af[mt], wf, acc[mt][ct], 0, 0, 0);
        }
    }
    const float gv = gamma[0];
    #pragma unroll
    for (int mt = 0; mt < 2; ++mt) {
        const int nr = n0 + 16 * mt + (lg << 2);
        const float4 rs4 = *reinterpret_cast<const float4*>(&rs[(size_t)b * NPIX + nr]);
        #pragma unroll
        for (int ct = 0; ct < 4; ++ct) {
            const int c = cb + 16 * ct + lr;
            const float bb = bv[c];
            ushort4 u;
            u.x = f2bf_rne(gv * rs4.x * (acc[mt][ct][0] + bb));
            u.y = f2bf_rne(gv * rs4.y * (acc[mt][ct][1] + bb));
            u.z = f2bf_rne(gv * rs4.z * (acc[mt][ct][2] + bb));
            u.w = f2bf_rne(gv * rs4.w * (acc[mt][ct][3] + bb));
            *reinterpret_cast<ushort4*>(&vt[((size_t)b * CIN + c) * NPIX + nr]) = u;
        }
    }
}

// ---------------------------------------------------------------------------
// K4: fused E^T -> exp2 -> PV, pipelined: per iteration PV(jb) || E(jb+1)
// in one region (MFMA pipe and VALU/exp2 overlap within each wave), single
// barrier per iter, distance-2 global prefetch of k/v fragments.
// Block: 64 i x 128 c, 4 waves. grid 512: b=n&3, ch=(n>>2)&1, it=n>>3.
// ---------------------------------------------------------------------------
__global__ __launch_bounds__(256, 2)
void out_kernel(const unsigned short* __restrict__ qt,
                const unsigned short* __restrict__ kt,
                const unsigned short* __restrict__ vt,
                const float* __restrict__ x, float* __restrict__ out)
{
    __shared__ unsigned short sP[2][64 * 64];   // [i][j] bf16, 128B rows, swizzled
    const int n = blockIdx.x;
    const int b = n & 3;
    const int rest = n >> 2;
    const int ch = rest & 1;
    const int it = rest >> 1;
    const int iblk = it * 64;
    const int cblk = ch * 128;
    const int t = threadIdx.x, w = t >> 6, l = t & 63, lr = l & 15, lg = l >> 4;
    const unsigned short* qb = qt + (size_t)b * NPIX * CATT;
    const unsigned short* kb = kt + (size_t)b * NPIX * CATT;
    const unsigned short* vb = vt + (size_t)b * CIN * NPIX;
    const f32x4 zero = {0.f, 0.f, 0.f, 0.f};

    bf16x8 qfrag[4];
    #pragma unroll
    for (int nt = 0; nt < 4; ++nt)
        qfrag[nt] = *reinterpret_cast<const bf16x8*>(
            &qb[(size_t)(iblk + 16 * nt + lr) * CATT + lg * 8]);

    const unsigned short* kp = kb + (size_t)(16 * w + lr) * CATT + lg * 8;
    const unsigned short* vp = vb + (size_t)(cblk + 32 * w + lr) * NPIX + lg * 8;

    const int swz = (lr & 7) << 4;
    const int wb0 = lr * 128 + (((16 * w + 4 * lg) * 2) ^ swz);
    const int rb_col0 = (16 * lg) ^ swz;
    const int rb_col1 = (64 + 16 * lg) ^ swz;

    f32x4 acc[2][4] = {};

    // ---- prologue: load tiles 0,1; compute E(0) -> sP[0]
    const bf16x8 kf0 = *reinterpret_cast<const bf16x8*>(kp);
    bf16x8 vc00 = *reinterpret_cast<const bf16x8*>(vp);
    bf16x8 vc01 = *reinterpret_cast<const bf16x8*>(vp + 32);
    bf16x8 vc10 = *reinterpret_cast<const bf16x8*>(vp + 16 * (size_t)NPIX);
    bf16x8 vc11 = *reinterpret_cast<const bf16x8*>(vp + 16 * (size_t)NPIX + 32);
    bf16x8 kfA  = *reinterpret_cast<const bf16x8*>(kp + (size_t)64 * CATT);
    bf16x8 vn00 = *reinterpret_cast<const bf16x8*>(vp + 64);
    bf16x8 vn01 = *reinterpret_cast<const bf16x8*>(vp + 64 + 32);
    bf16x8 vn10 = *reinterpret_cast<const bf16x8*>(vp + 16 * (size_t)NPIX + 64);
    bf16x8 vn11 = *reinterpret_cast<const bf16x8*>(vp + 16 * (size_t)NPIX + 64 + 32);
    {
        char* spw = reinterpret_cast<char*>(&sP[0][0]);
        #pragma unroll
        for (int nt = 0; nt < 4; ++nt) {
            const f32x4 e = __builtin_amdgcn_mfma_f32_16x16x32_bf16(kf0, qfrag[nt], zero, 0, 0, 0);
            const float p0 = __builtin_amdgcn_exp2f(e[0]);
            const float p1 = __builtin_amdgcn_exp2f(e[1]);
            const float p2 = __builtin_amdgcn_exp2f(e[2]);
            const float p3 = __builtin_amdgcn_exp2f(e[3]);
            unsigned w0, w1;
            asm("v_cvt_pk_bf16_f32 %0, %1, %2" : "=v"(w0) : "v"(p0), "v"(p1));
            asm("v_cvt_pk_bf16_f32 %0, %1, %2" : "=v"(w1) : "v"(p2), "v"(p3));
            *reinterpret_cast<uint2*>(spw + wb0 + nt * 2048) = make_uint2(w0, w1);
        }
    }
    __syncthreads();

    // ---- main loop: iter jb does PV(jb) + E(jb+1), one barrier
    for (int jb = 0; jb < 63; ++jb) {
        const int jpre = (jb + 2 < 64) ? jb + 2 : 63;
        const bf16x8 kfN  = *reinterpret_cast<const bf16x8*>(kp + (size_t)jpre * 64 * CATT);
        const unsigned short* vpp = vp + (size_t)jpre * 64;
        const bf16x8 vN00 = *reinterpret_cast<const bf16x8*>(vpp);
        const bf16x8 vN01 = *reinterpret_cast<const bf16x8*>(vpp + 32);
        const bf16x8 vN10 = *reinterpret_cast<const bf16x8*>(vpp + 16 * (size_t)NPIX);
        const bf16x8 vN11 = *reinterpret_cast<const bf16x8*>(vpp + 16 * (size_t)NPIX + 32);

        char* spw = reinterpret_cast<char*>(&sP[(jb + 1) & 1][0]);
        char* spr = reinterpret_cast<char*>(&sP[jb & 1][0]);

        // E(jb+1) MFMAs (feed exp2 later; independent of PV below)
        f32x4 e[4];
        #pragma unroll
        for (int nt = 0; nt < 4; ++nt)
            e[nt] = __builtin_amdgcn_mfma_f32_16x16x32_bf16(kfA, qfrag[nt], zero, 0, 0, 0);

        // PV(jb) kk=0
        bf16x8 pf[4];
        #pragma unroll
        for (int nt = 0; nt < 4; ++nt)
            pf[nt] = *reinterpret_cast<const bf16x8*>(spr + lr * 128 + nt * 2048 + rb_col0);
        __builtin_amdgcn_s_setprio(1);
        #pragma unroll
        for (int nt = 0; nt < 4; ++nt) {
            acc[0][nt] = __builtin_amdgcn_mfma_f32_16x16x32_bf16(vc00, pf[nt], acc[0][nt], 0, 0, 0);
            acc[1][nt] = __builtin_amdgcn_mfma_f32_16x16x32_bf16(vc10, pf[nt], acc[1][nt], 0, 0, 0);
        }
        __builtin_amdgcn_s_setprio(0);
        // exp2/cvt/store for e[0], e[1] (VALU overlaps MFMA above/below)
        #pragma unroll
        for (int h = 0; h < 2; ++h) {
            const float p0 = __builtin_amdgcn_exp2f(e[h][0]);
            const float p1 = __builtin_amdgcn_exp2f(e[h][1]);
            const float p2 = __builtin_amdgcn_exp2f(e[h][2]);
            const float p3 = __builtin_amdgcn_exp2f(e[h][3]);
            unsigned w0, w1;
            asm("v_cvt_pk_bf16_f32 %0, %1, %2" : "=v"(w0) : "v"(p0), "v"(p1));
            asm("v_cvt_pk_bf16_f32 %0, %1, %2" : "=v"(w1) : "v"(p2), "v"(p3));
            *reinterpret_cast<uint2*>(spw + wb0 + h * 2048) = make_uint2(w0, w1);
        }
        // PV(jb) kk=1
        #pragma unroll
        for (int nt = 0; nt < 4; ++nt)
            pf[nt] = *reinterpret_cast<const bf16x8*>(spr + lr * 128 + nt * 2048 + rb_col1);
        __builtin_amdgcn_s_setprio(1);
        #pragma unroll
        for (int nt = 0; nt < 4; ++nt) {
            acc[0][nt] = __builtin_amdgcn_mfma_f32_16x16x32_bf16(vc01, pf[nt], acc[0][nt], 0, 0, 0);
            acc[1][nt] = __builtin_amdgcn_mfma_f32_16x16x32_bf16(vc11, pf[nt], acc[1][nt], 0, 0, 0);
        }
        __builtin_amdgcn_s_setprio(0);
        // exp2/cvt/store for e[2], e[3]
        #pragma unroll
        for (int h = 2; h < 4; ++h) {
            const float p0 = __builtin_amdgcn_exp2f(e[h][0]);
            const float p1 = __builtin_amdgcn_exp2f(e[h][1]);
            const float p2 = __builtin_amdgcn_exp2f(e[h][2]);
            const float p3 = __builtin_amdgcn_exp2f(e[h][3]);
            unsigned w0, w1;
            asm("v_cvt_pk_bf16_f32 %0, %1, %2" : "=v"(w0) : "v"(p0), "v"(p1));
            asm("v_cvt_pk_bf16_f32 %0, %1, %2" : "=v"(w1) : "v"(p2), "v"(p3));
            *reinterpret_cast<uint2*>(spw + wb0 + h * 2048) = make_uint2(w0, w1);
        }
        __syncthreads();
        kfA = kfN;
        vc00 = vn00; vc01 = vn01; vc10 = vn10; vc11 = vn11;
        vn00 = vN00; vn01 = vN01; vn10 = vN10; vn11 = vN11;
    }

    // ---- epilogue: PV(63) from sP[1]
    {
        char* spr = reinterpret_cast<char*>(&sP[1][0]);
        bf16x8 pf[4];
        #pragma unroll
        for (int nt = 0; nt < 4; ++nt)
            pf[nt] = *reinterpret_cast<const bf16x8*>(spr + lr * 128 + nt * 2048 + rb_col0);
        #pragma unroll
        for (int nt = 0; nt < 4; ++nt) {
            acc[0][nt] = __builtin_amdgcn_mfma_f32_16x16x32_bf16(vc00, pf[nt], acc[0][nt], 0, 0, 0);
            acc[1][nt] = __builtin_amdgcn_mfma_f32_16x16x32_bf16(vc10, pf[nt], acc[1][nt], 0, 0, 0);
        }
        #pragma unroll
        for (int nt = 0; nt < 4; ++nt)
            pf[nt] = *reinterpret_cast<const bf16x8*>(spr + lr * 128 + nt * 2048 + rb_col1);
        #pragma unroll
        for (int nt = 0; nt < 4; ++nt) {
            acc[0][nt] = __builtin_amdgcn_mfma_f32_16x16x32_bf16(vc01, pf[nt], acc[0][nt], 0, 0, 0);
            acc[1][nt] = __builtin_amdgcn_mfma_f32_16x16x32_bf16(vc11, pf[nt], acc[1][nt], 0, 0, 0);
        }
    }

    const float* xb = x + (size_t)b * CIN * NPIX;
    float* ob = out + (size_t)b * CIN * NPIX;
    #pragma unroll
    for (int mt = 0; mt < 2; ++mt)
        #pragma unroll
        for (int nt = 0; nt < 4; ++nt)
            #pragma unroll
            for (int r = 0; r < 4; ++r) {
                const int c = cblk + 32 * w + 16 * mt + (lg << 2) + r;
                const size_t idx = (size_t)c * NPIX + iblk + 16 * nt + lr;
                ob[idx] = acc[mt][nt][r] + xb[idx];
            }
}

// ---------------------------------------------------------------------------
extern "C" void kernel_launch(void* const* d_in, const int* in_sizes, int n_in,
                              void* d_out, int out_size, void* d_ws, size_t ws_size,
                              hipStream_t stream)
{
    const float* x     = (const float*)d_in[0];
    const float* Wq    = (const float*)d_in[1];
    const float* bq    = (const float*)d_in[2];
    const float* Wk    = (const float*)d_in[3];
    const float* bk    = (const float*)d_in[4];
    const float* Wv    = (const float*)d_in[5];
    const float* bv    = (const float*)d_in[6];
    const float* gamma = (const float*)d_in[7];
    float* out = (float*)d_out;

    // workspace: xT bf16 [b][n][256] | qt,kt bf16 [b][n][32] | vt bf16 [b][c][n] | rs f32  ~18.4 MB
    unsigned short* xT = (unsigned short*)d_ws;
    unsigned short* qt = xT + (size_t)NBATCH * NPIX * CIN;
    unsigned short* kt = qt + (size_t)NBATCH * NPIX * CATT;
    unsigned short* vt = kt + (size_t)NBATCH * NPIX * CATT;
    float* rsw = (float*)(vt + (size_t)NBATCH * CIN * NPIX);

    transpose_kernel<<<dim3(NPIX / 64, CIN / 64, NBATCH), 256, 0, stream>>>(x, xT);
    proj_qk_kernel<<<dim3(NPIX / 64, NBATCH), 256, 0, stream>>>(Wq, bq, Wk, bk, xT, qt, kt);
    stats_kernel<<<dim3((NPIX / 32) * NBATCH), 256, 0, stream>>>(qt, kt, rsw);
    proj_v_kernel<<<dim3(NPIX / 32, NBATCH), 256, 0, stream>>>(Wv, bv, xT, rsw, gamma, vt);
    out_kernel<<<dim3((NPIX / 64) * 2 * NBATCH), 256, 0, stream>>>(qt, kt, vt, x, out);
}